// Round 4
// baseline (15135.452 us; speedup 1.0000x reference)
//
#include <hip/hip_runtime.h>
#include <hip/hip_bf16.h>

typedef unsigned int  u32;
typedef unsigned short u16;
typedef unsigned long long u64;
typedef float f32x16 __attribute__((ext_vector_type(16)));
typedef short bf16x8 __attribute__((ext_vector_type(8)));

#define TT 512
#define BBATCH 32

// ---------- helpers ----------
__device__ __forceinline__ float bfu2f(u16 u){
  union { u32 i; float f; } v; v.i = ((u32)u) << 16; return v.f;
}
__device__ __forceinline__ u16 f2bf_u(float f){
  union { float f; u32 i; } v; v.f = f;
  u32 r = v.i + 0x7fffu + ((v.i >> 16) & 1u);   // RNE
  return (u16)(r >> 16);
}
__device__ __forceinline__ float rcp_fast(float x){
  float r; asm("v_rcp_f32 %0, %1" : "=v"(r) : "v"(x)); return r;
}
__device__ __forceinline__ float sigm(float x){
  return rcp_fast(1.f + __expf(-x));
}
__device__ __forceinline__ float tanh_s(float x){
  float ax = fabsf(x);
  float e = __expf(-2.f * ax);
  float t = (1.f - e) * rcp_fast(1.f + e);
  return copysignf(t, x);
}
// DPP quad_perm cross-lane (VALU pipe, no LDS)
__device__ __forceinline__ float dppq_xor1(float v){
  union { float f; int i; } a, r; a.f = v;
  r.i = __builtin_amdgcn_mov_dpp(a.i, 0xB1, 0xF, 0xF, true);  // (1,0,3,2)
  return r.f;
}
__device__ __forceinline__ float dppq_xor2(float v){
  union { float f; int i; } a, r; a.f = v;
  r.i = __builtin_amdgcn_mov_dpp(a.i, 0x4E, 0xF, 0xF, true);  // (2,3,0,1)
  return r.f;
}

#define SWZ(m) ((u32)(((m) & 15) << 4))

// ---------- fp32 -> bf16 weight convert ----------
__global__ void tobf16(const float* __restrict__ src, u16* __restrict__ dst, int n)
{
  int i = blockIdx.x * blockDim.x + threadIdx.x;
  if (i < n) dst[i] = f2bf_u(src[i]);
}

__global__ void zflags(u32* flags)
{
  flags[blockIdx.x * 256 + threadIdx.x] = 0;
}

// ---------- projection GEMM ----------
// A fp32 or bf16 (abf). Writes either:
//  Cx (bf16): gate-interleaved C-fragment layout xc[t][s][b], s = e*4+g,
//             g = n>>nshift, e = n & ((1<<nshift)-1)
//  Cf (f32):  Cf + b*c_sb + t*c_st + n
#define BM 128
#define BN 128
#define BK 32

__global__ __launch_bounds__(256) void proj(
    const void* __restrict__ A, int abf, long a_st, long a_sb, int flip, int K,
    const float* __restrict__ W, const float* __restrict__ bias, int N, int nshift,
    u16* __restrict__ Cx, float* __restrict__ Cf, long c_sb, long c_st)
{
  __shared__ float As[BK][BM + 4];
  __shared__ float Bs[BK][BN + 4];
  const int n0 = blockIdx.x * BN;
  const int m0 = blockIdx.y * BM;
  const int tid = threadIdx.x;
  const int tx = tid & 15, ty = tid >> 4;
  const int lr = tid >> 3;          // 0..31
  const int lc = (tid & 7) * 4;     // 0,4,...,28

  float acc[8][8];
#pragma unroll
  for (int i = 0; i < 8; ++i)
#pragma unroll
    for (int j = 0; j < 8; ++j) acc[i][j] = 0.f;

  const char* arowb[4];
  const int esz = abf ? 2 : 4;
#pragma unroll
  for (int rr = 0; rr < 4; ++rr){
    int m = m0 + lr + rr * 32;
    int t = m >> 5, b = m & 31;
    int tq = flip ? (TT - 1 - t) : t;
    arowb[rr] = (const char*)A + ((size_t)tq * a_st + (size_t)b * a_sb) * esz;
  }

  for (int k0 = 0; k0 < K; k0 += BK){
#pragma unroll
    for (int rr = 0; rr < 4; ++rr){
      int m = lr + rr * 32;
      if (abf){
        ushort4 v = *(const ushort4*)((const u16*)arowb[rr] + k0 + lc);
        As[lc + 0][m] = bfu2f(v.x); As[lc + 1][m] = bfu2f(v.y);
        As[lc + 2][m] = bfu2f(v.z); As[lc + 3][m] = bfu2f(v.w);
      } else {
        float4 v = *(const float4*)((const float*)arowb[rr] + k0 + lc);
        As[lc + 0][m] = v.x; As[lc + 1][m] = v.y;
        As[lc + 2][m] = v.z; As[lc + 3][m] = v.w;
      }
    }
#pragma unroll
    for (int rr = 0; rr < 4; ++rr){
      int n = n0 + lr + rr * 32;
      float4 v = *(const float4*)(W + (size_t)n * K + k0 + lc);
      int nl = lr + rr * 32;
      Bs[lc + 0][nl] = v.x; Bs[lc + 1][nl] = v.y;
      Bs[lc + 2][nl] = v.z; Bs[lc + 3][nl] = v.w;
    }
    __syncthreads();
#pragma unroll
    for (int kk = 0; kk < BK; ++kk){
      float4 a0 = *(const float4*)&As[kk][ty * 8];
      float4 a1 = *(const float4*)&As[kk][ty * 8 + 4];
      float4 b0 = *(const float4*)&Bs[kk][tx * 8];
      float4 b1 = *(const float4*)&Bs[kk][tx * 8 + 4];
      float am[8] = {a0.x,a0.y,a0.z,a0.w,a1.x,a1.y,a1.z,a1.w};
      float bn[8] = {b0.x,b0.y,b0.z,b0.w,b1.x,b1.y,b1.z,b1.w};
#pragma unroll
      for (int i = 0; i < 8; ++i)
#pragma unroll
        for (int j = 0; j < 8; ++j)
          acc[i][j] += am[i] * bn[j];
    }
    __syncthreads();
  }

  float bj[8];
#pragma unroll
  for (int j = 0; j < 8; ++j) bj[j] = bias ? bias[n0 + tx * 8 + j] : 0.f;

  if (Cx){
    // rows m0+ty*8 .. +8 share t; b consecutive → 16B store per n
    const int mbase = m0 + ty * 8;
    const int t = mbase >> 5, b0 = mbase & 31;
    const int emask = (1 << nshift) - 1;
#pragma unroll
    for (int j = 0; j < 8; ++j){
      int n = n0 + tx * 8 + j;
      int s = ((n & emask) << 2) | (n >> nshift);
      u16 tmp[8];
#pragma unroll
      for (int i = 0; i < 8; ++i) tmp[i] = f2bf_u(acc[i][j] + bj[j]);
      *(uint4*)(Cx + ((size_t)t * N + s) * 32 + b0) = *(uint4*)tmp;
    }
  } else {
#pragma unroll
    for (int i = 0; i < 8; ++i){
      int m = m0 + ty * 8 + i;
      int t = m >> 5, b = m & 31;
      float* dst = Cf + (size_t)b * c_sb + (size_t)t * c_st + n0 + tx * 8;
      float4 v0 = {acc[i][0] + bj[0], acc[i][1] + bj[1], acc[i][2] + bj[2], acc[i][3] + bj[3]};
      float4 v1 = {acc[i][4] + bj[4], acc[i][5] + bj[5], acc[i][6] + bj[6], acc[i][7] + bj[7]};
      *(float4*)(dst)     = v0;
      *(float4*)(dst + 4) = v1;
    }
  }
}

// ---------- encoder scan: gate-interleaved, in-register pointwise ----------
// blocks at bx = q*8 + dir (dir<2, q<4). Wd bf16 [1024][256] raw torch rows.
// xc[t][s][b] bf16, s = e*4+g (e global 0..255). exch u16 [row][512].
__global__ __launch_bounds__(512, 2) void scan_enc3(
    const u16* __restrict__ WF, const u16* __restrict__ WB,
    const u16* __restrict__ xcF, const u16* __restrict__ xcB,
    u16* __restrict__ exch, u32* __restrict__ flags)
{
  const int bx = blockIdx.x;
  const int dir = bx & 7;
  if (dir >= 2) return;
  const int q = bx >> 3;
  const u16* __restrict__ Wd = dir ? WB : WF;
  const u16* __restrict__ xc = dir ? xcB : xcF;
  const int tid = threadIdx.x;
  const int l = tid & 63, w = tid >> 6;
  const int l31 = l & 31, hi = l >> 5, p = l & 3;

  __shared__ u16 hA[2][32 * 256];   // double-buffered h[b][k], swizzled

  // persistent B fragments (gate-interleaved col order)
  const int n_local = w * 32 + l31;
  const int grow = (n_local & 3) * 256 + 64 * q + (n_local >> 2);
  const int kbase = hi << 3;
  bf16x8 bfr[16];
#pragma unroll
  for (int ks = 0; ks < 16; ++ks)
    bfr[ks] = *reinterpret_cast<const bf16x8*>(Wd + (size_t)grow * 256 + ks * 16 + kbase);

  const int e = 64 * q + 8 * w + (l31 >> 2);
  const int scol = 256 * q + n_local;
  const u64* __restrict__ xc64 = (const u64*)xc;

  char* hAb = (char*)hA;
  const int abase = l31 * 512 + (hi << 4);
  const u32 aswz = SWZ(l31);

  float c[4] = {0.f, 0.f, 0.f, 0.f};

  u64 px[4];
#pragma unroll
  for (int rq = 0; rq < 4; ++rq)
    px[rq] = xc64[(size_t)scol * 8 + 2 * rq + hi];

  const int flb = dir * 16;   // flag slot base (×32 u32 each)

  for (int t = 0; t < TT; ++t){
    f32x16 acc0, acc1;
#pragma unroll
    for (int rq = 0; rq < 4; ++rq){
      u64 v = px[rq];
      acc0[4 * rq + 0] = bfu2f((u16)(v));
      acc0[4 * rq + 1] = bfu2f((u16)(v >> 16));
      acc0[4 * rq + 2] = bfu2f((u16)(v >> 32));
      acc0[4 * rq + 3] = bfu2f((u16)(v >> 48));
      acc1[4 * rq + 0] = 0.f; acc1[4 * rq + 1] = 0.f;
      acc1[4 * rq + 2] = 0.f; acc1[4 * rq + 3] = 0.f;
    }
    { // prefetch xc(t+1)
      int tn = (t + 1 < TT) ? t + 1 : t;
#pragma unroll
      for (int rq = 0; rq < 4; ++rq)
        px[rq] = xc64[((size_t)tn * 1024 + scol) * 8 + 2 * rq + hi];
    }
    if (t > 0){
      const char* hb = hAb + (size_t)(t & 1) * 16384;
#pragma unroll
      for (int ks = 0; ks < 16; ks += 2){
        bf16x8 aA = *(const bf16x8*)(hb + ((u32)(abase + ks * 32) ^ aswz));
        bf16x8 aB = *(const bf16x8*)(hb + ((u32)(abase + ks * 32 + 32) ^ aswz));
        acc0 = __builtin_amdgcn_mfma_f32_32x32x16_bf16(aA, bfr[ks],     acc0, 0, 0, 0);
        acc1 = __builtin_amdgcn_mfma_f32_32x32x16_bf16(aB, bfr[ks + 1], acc1, 0, 0, 0);
      }
    }
    float vals[16], v1[16], v2[16];
#pragma unroll
    for (int r = 0; r < 16; ++r) vals[r] = acc0[r] + acc1[r];
    // quad transpose: v2[4g+k] = gate g of cell m = 8p+4hi+k (e fixed)
#pragma unroll
    for (int r = 0; r < 16; ++r){
      float tmp = dppq_xor1(vals[r ^ 4]);
      v1[r] = (((l & 1) ^ ((r >> 2) & 1)) != 0) ? tmp : vals[r];
    }
#pragma unroll
    for (int r = 0; r < 16; ++r){
      float tmp = dppq_xor2(v1[r ^ 8]);
      v2[r] = ((((l >> 1) & 1) ^ ((r >> 3) & 1)) != 0) ? tmp : v1[r];
    }
    // pointwise: 4 cells (m = 8p+4hi+k, e)
    u16 hb16[4];
#pragma unroll
    for (int k = 0; k < 4; ++k){
      float i_ = sigm(v2[k]);
      float f_ = sigm(v2[4 + k]);
      float g_ = tanh_s(v2[8 + k]);
      float o_ = sigm(v2[12 + k]);
      c[k] = f_ * c[k] + i_ * g_;
      hb16[k] = f2bf_u(o_ * tanh_s(c[k]));
    }
    const int rowbase = (dir ? (TT - 1 - t) : t) * 32;
    char* hw = hAb + (size_t)((t + 1) & 1) * 16384;
#pragma unroll
    for (int k = 0; k < 4; ++k){
      int m = 8 * p + 4 * hi + k;
      exch[(size_t)(rowbase + m) * 512 + dir * 256 + e] = hb16[k];
      *(u16*)(hw + ((u32)(m * 512 + 2 * e) ^ SWZ(m))) = hb16[k];
    }
    if (t == TT - 1) break;

    __syncthreads();   // drains exch stores (vmcnt) + hA own writes visible
    if (tid == 0)
      __hip_atomic_store(&flags[(flb + q) * 32], (u32)(t + 1),
                         __ATOMIC_RELEASE, __HIP_MEMORY_SCOPE_AGENT);
    { // all threads spin on 3 sibling flags (each in own 128B line)
      const int r0 = (q + 1) & 3, r1 = (q + 2) & 3, r2 = (q + 3) & 3;
      const u32 tgt = (u32)(t + 1);
      while (true){
        u32 a0 = __hip_atomic_load(&flags[(flb + r0) * 32], __ATOMIC_ACQUIRE, __HIP_MEMORY_SCOPE_AGENT);
        u32 a1 = __hip_atomic_load(&flags[(flb + r1) * 32], __ATOMIC_ACQUIRE, __HIP_MEMORY_SCOPE_AGENT);
        u32 a2 = __hip_atomic_load(&flags[(flb + r2) * 32], __ATOMIC_ACQUIRE, __HIP_MEMORY_SCOPE_AGENT);
        if (a0 >= tgt && a1 >= tgt && a2 >= tgt) break;
      }
    }
    { // stage 3 remote quarters (1536 u64) into next hA
      const u64* __restrict__ ex64 = (const u64*)exch;
#pragma unroll
      for (int it = 0; it < 3; ++it){
        int j = tid + it * 512;
        int rqi = j >> 9;
        int rq = rqi + (rqi >= q ? 1 : 0);
        int rem = j & 511;
        int b2 = rem >> 4;
        int u8i = rem & 15;
        u64 v = __hip_atomic_load(ex64 + (size_t)(rowbase + b2) * 128 + dir * 64 + rq * 16 + u8i,
                                  __ATOMIC_RELAXED, __HIP_MEMORY_SCOPE_AGENT);
        *(u64*)(hw + ((u32)(b2 * 512 + rq * 128 + u8i * 8) ^ SWZ(b2))) = v;
      }
    }
    __syncthreads();
  }
}

// ---------- decoder scan: single block, gate-interleaved, 1 barrier/step ----------
// Wd bf16 [512][128] raw torch rows. xc[t][s][b], s = e*4+g. yb f32 [m][128].
__global__ __launch_bounds__(512, 2) void scan_dec3(
    const u16* __restrict__ Wd, const u16* __restrict__ xc, float* __restrict__ yb)
{
  const int tid = threadIdx.x;
  const int l = tid & 63, w = tid >> 6;
  const int l31 = l & 31, hi = l >> 5, p = l & 3;

  __shared__ u16 hA[2][32 * 128];

  const int n0 = 64 * w + l31;
  const int n1 = n0 + 32;
  const int grow0 = (n0 & 3) * 128 + (n0 >> 2);
  const int grow1 = (n1 & 3) * 128 + (n1 >> 2);
  const int kbase = hi << 3;
  bf16x8 bf0[8], bf1[8];
#pragma unroll
  for (int ks = 0; ks < 8; ++ks){
    bf0[ks] = *reinterpret_cast<const bf16x8*>(Wd + (size_t)grow0 * 128 + ks * 16 + kbase);
    bf1[ks] = *reinterpret_cast<const bf16x8*>(Wd + (size_t)grow1 * 128 + ks * 16 + kbase);
  }
  const int e0 = 16 * w + (l31 >> 2);
  const int e1 = e0 + 8;
  const u64* __restrict__ xc64 = (const u64*)xc;

  char* hAb = (char*)hA;
  const int abase = l31 * 256 + (hi << 4);
  const u32 aswz = SWZ(l31);

  float c[8];
#pragma unroll
  for (int i = 0; i < 8; ++i) c[i] = 0.f;

  u64 px0[4], px1[4];
#pragma unroll
  for (int rq = 0; rq < 4; ++rq){
    px0[rq] = xc64[(size_t)n0 * 8 + 2 * rq + hi];
    px1[rq] = xc64[(size_t)n1 * 8 + 2 * rq + hi];
  }

  for (int t = 0; t < TT; ++t){
    f32x16 acc0, acc1;
#pragma unroll
    for (int rq = 0; rq < 4; ++rq){
      u64 v0 = px0[rq], v1l = px1[rq];
      acc0[4 * rq + 0] = bfu2f((u16)(v0));       acc1[4 * rq + 0] = bfu2f((u16)(v1l));
      acc0[4 * rq + 1] = bfu2f((u16)(v0 >> 16)); acc1[4 * rq + 1] = bfu2f((u16)(v1l >> 16));
      acc0[4 * rq + 2] = bfu2f((u16)(v0 >> 32)); acc1[4 * rq + 2] = bfu2f((u16)(v1l >> 32));
      acc0[4 * rq + 3] = bfu2f((u16)(v0 >> 48)); acc1[4 * rq + 3] = bfu2f((u16)(v1l >> 48));
    }
    { // prefetch xc(t+1)
      int tn = (t + 1 < TT) ? t + 1 : t;
#pragma unroll
      for (int rq = 0; rq < 4; ++rq){
        px0[rq] = xc64[((size_t)tn * 512 + n0) * 8 + 2 * rq + hi];
        px1[rq] = xc64[((size_t)tn * 512 + n1) * 8 + 2 * rq + hi];
      }
    }
    if (t > 0){
      const char* hb = hAb + (size_t)(t & 1) * 8192;
#pragma unroll
      for (int ks = 0; ks < 8; ++ks){
        bf16x8 aA = *(const bf16x8*)(hb + ((u32)(abase + ks * 32) ^ aswz));
        acc0 = __builtin_amdgcn_mfma_f32_32x32x16_bf16(aA, bf0[ks], acc0, 0, 0, 0);
        acc1 = __builtin_amdgcn_mfma_f32_32x32x16_bf16(aA, bf1[ks], acc1, 0, 0, 0);
      }
    }
    char* hw = hAb + (size_t)((t + 1) & 1) * 8192;
#pragma unroll
    for (int a = 0; a < 2; ++a){
      float vals[16], v1[16], v2[16];
#pragma unroll
      for (int r = 0; r < 16; ++r) vals[r] = a ? acc1[r] : acc0[r];
#pragma unroll
      for (int r = 0; r < 16; ++r){
        float tmp = dppq_xor1(vals[r ^ 4]);
        v1[r] = (((l & 1) ^ ((r >> 2) & 1)) != 0) ? tmp : vals[r];
      }
#pragma unroll
      for (int r = 0; r < 16; ++r){
        float tmp = dppq_xor2(v1[r ^ 8]);
        v2[r] = ((((l >> 1) & 1) ^ ((r >> 3) & 1)) != 0) ? tmp : v1[r];
      }
      const int ea = a ? e1 : e0;
#pragma unroll
      for (int k = 0; k < 4; ++k){
        float i_ = sigm(v2[k]);
        float f_ = sigm(v2[4 + k]);
        float g_ = tanh_s(v2[8 + k]);
        float o_ = sigm(v2[12 + k]);
        int ci = a * 4 + k;
        c[ci] = f_ * c[ci] + i_ * g_;
        float h = o_ * tanh_s(c[ci]);
        int m = 8 * p + 4 * hi + k;
        yb[((size_t)(t * 32 + m)) * 128 + ea] = h;
        *(u16*)(hw + ((u32)(m * 256 + 2 * ea) ^ SWZ(m))) = f2bf_u(h);
      }
    }
    __syncthreads();
  }
}

extern "C" void kernel_launch(void* const* d_in, const int* in_sizes, int n_in,
                              void* d_out, int out_size, void* d_ws, size_t ws_size,
                              hipStream_t stream)
{
  const float* x        = (const float*)d_in[0];
  const float* e0f_Wih  = (const float*)d_in[1];
  const float* e0f_Whh  = (const float*)d_in[2];
  const float* e0f_b    = (const float*)d_in[3];
  const float* e0b_Wih  = (const float*)d_in[4];
  const float* e0b_Whh  = (const float*)d_in[5];
  const float* e0b_b    = (const float*)d_in[6];
  const float* e1f_Wih  = (const float*)d_in[7];
  const float* e1f_Whh  = (const float*)d_in[8];
  const float* e1f_b    = (const float*)d_in[9];
  const float* e1b_Wih  = (const float*)d_in[10];
  const float* e1b_Whh  = (const float*)d_in[11];
  const float* e1b_b    = (const float*)d_in[12];
  const float* dec_Wih  = (const float*)d_in[13];
  const float* dec_Whh  = (const float*)d_in[14];
  const float* dec_b    = (const float*)d_in[15];
  const float* out_W    = (const float*)d_in[16];
  const float* out_b    = (const float*)d_in[17];

  char* p = (char*)d_ws;
  auto alloc = [&](size_t bytes){
    void* r = (void*)p;
    p += (bytes + 255) & ~(size_t)255;
    return r;
  };
  const size_t M = (size_t)TT * BBATCH;          // 16384
  u16* xcA  = (u16*)alloc((size_t)TT * 1024 * 32 * 2);   // 33.6 MB
  u16* xcB  = (u16*)alloc((size_t)TT * 1024 * 32 * 2);   // 33.6 MB
  u16* exch = (u16*)alloc(M * 512 * 2);                  // 16.8 MB
  float* yb = (float*)alloc(M * 128 * 4);
  u16* wE0f = (u16*)alloc(1024 * 256 * 2);
  u16* wE0b = (u16*)alloc(1024 * 256 * 2);
  u16* wE1f = (u16*)alloc(1024 * 256 * 2);
  u16* wE1b = (u16*)alloc(1024 * 256 * 2);
  u16* wDec = (u16*)alloc(512 * 128 * 2);
  u32* flags = (u32*)alloc(2048 * 4);                    // 2 layers × 2 dirs × 4q × 128B

  zflags<<<8, 256, 0, stream>>>(flags);
  tobf16<<<1024, 256, 0, stream>>>(e0f_Whh, wE0f, 1024 * 256);
  tobf16<<<1024, 256, 0, stream>>>(e0b_Whh, wE0b, 1024 * 256);
  tobf16<<<1024, 256, 0, stream>>>(e1f_Whh, wE1f, 1024 * 256);
  tobf16<<<1024, 256, 0, stream>>>(e1b_Whh, wE1b, 1024 * 256);
  tobf16<<<256,  256, 0, stream>>>(dec_Whh, wDec, 512 * 128);

  // encoder layer 0 projections: x [B,T,128] f32 -> xc
  proj<<<dim3(8, 128), 256, 0, stream>>>(x, 0, 128, (long)TT * 128, 0, 128,
      e0f_Wih, e0f_b, 1024, 8, xcA, nullptr, 0, 0);
  proj<<<dim3(8, 128), 256, 0, stream>>>(x, 0, 128, (long)TT * 128, 1, 128,
      e0b_Wih, e0b_b, 1024, 8, xcB, nullptr, 0, 0);
  scan_enc3<<<32, 512, 0, stream>>>(wE0f, wE0b, xcA, xcB, exch, flags);

  // encoder layer 1 projections: A = exch bf16 [t*32+b][512]
  proj<<<dim3(8, 128), 256, 0, stream>>>(exch, 1, (long)BBATCH * 512, 512, 0, 512,
      e1f_Wih, e1f_b, 1024, 8, xcA, nullptr, 0, 0);
  proj<<<dim3(8, 128), 256, 0, stream>>>(exch, 1, (long)BBATCH * 512, 512, 1, 512,
      e1b_Wih, e1b_b, 1024, 8, xcB, nullptr, 0, 0);
  scan_enc3<<<32, 512, 0, stream>>>(wE1f, wE1b, xcA, xcB, exch, flags + 1024);

  // decoder projection: A = exch (layer-1 h) bf16, N=512 -> xcA
  proj<<<dim3(4, 128), 256, 0, stream>>>(exch, 1, (long)BBATCH * 512, 512, 0, 512,
      dec_Wih, dec_b, 512, 7, xcA, nullptr, 0, 0);
  scan_dec3<<<1, 512, 0, stream>>>(wDec, xcA, yb);

  // output linear: yb f32 [t*32+b][128] -> d_out [B,T,128] f32
  proj<<<dim3(1, 128), 256, 0, stream>>>(yb, 0, (long)BBATCH * 128, 128, 0, 128,
      out_W, out_b, 128, 0, nullptr, (float*)d_out, (long)TT * 128, 128);
}